// Round 5
// baseline (130.393 us; speedup 1.0000x reference)
//
#include <hip/hip_runtime.h>
#include <math.h>

#define NCOLS 5000
#define NF4   1250            // NCOLS / 4
#define BLOCK 512
#define NWAVES (BLOCK / 64)
#define NITER 3               // ceil(NF4 / BLOCK)
#define TOPKK 10
#define CAP 256               // candidate-list capacity (expected ~30-80)

// Monotone-ascending mapping float -> uint32 (total order on finite floats).
__device__ __forceinline__ unsigned mono_f32(float f) {
  unsigned u = __float_as_uint(f);
  return (u & 0x80000000u) ? ~u : (u | 0x80000000u);
}

__device__ __forceinline__ float wave_sum_f(float v) {
#pragma unroll
  for (int o = 1; o < 64; o <<= 1) v += __shfl_xor(v, o);
  return v;
}
__device__ __forceinline__ int wave_sum_i(int v) {
#pragma unroll
  for (int o = 1; o < 64; o <<= 1) v += __shfl_xor(v, o);
  return v;
}
__device__ __forceinline__ unsigned wave_max_u(unsigned v) {
#pragma unroll
  for (int o = 1; o < 64; o <<= 1) {
    unsigned w = __shfl_xor(v, o);
    v = w > v ? w : v;
  }
  return v;
}

extern "C" __global__ __launch_bounds__(BLOCK, 4)
void row_loss_kernel(const float* __restrict__ up, const float* __restrict__ down,
                     const float* __restrict__ yt, const int* __restrict__ masks,
                     float* __restrict__ out, float inv_nrows) {
  __shared__ float red_f[6][NWAVES];     // sq, sp, seyy, seyu, aspu, aspd
  __shared__ int red_i[NWAVES];          // nv partials
  __shared__ unsigned t1w_t[NWAVES];     // per-wave 10th-largest thread-max (top keys)
  __shared__ unsigned t1w_b[NWAVES];     // same for bottom keys (~key)
  __shared__ unsigned keys_t[CAP];       // top candidates: key
  __shared__ float    vals_t[CAP];       //                 u
  __shared__ unsigned keys_b[CAP];       // bottom candidates: ~key
  __shared__ float    vals_b[CAP];       //                    d
  __shared__ int ct, cb;
  __shared__ float s_res[2];             // SU, SD

  const int tid = threadIdx.x;
  const int lane = tid & 63;
  const int wv = tid >> 6;
  const long long b4 = (long long)blockIdx.x * NF4;

  const float4* up4 = (const float4*)up + b4;
  const float4* dn4 = (const float4*)down + b4;
  const float4* yt4 = (const float4*)yt + b4;
  const int4*   mk4 = (const int4*)masks + b4;

  if (tid == 0) { ct = 0; cb = 0; }

  // ---- Issue all global loads up front (12 outstanding float4 loads).
  float4 y4[NITER], u4[NITER], d4[NITER];
  int4 m4[NITER];
#pragma unroll
  for (int j = 0; j < NITER; ++j) {
    const int f = j * BLOCK + tid;
    if (f < NF4) {
      y4[j] = yt4[f]; u4[j] = up4[f]; d4[j] = dn4[f]; m4[j] = mk4[f];
    } else {
      y4[j] = make_float4(0.f, 0.f, 0.f, 0.f);
      u4[j] = y4[j]; d4[j] = y4[j];
      m4[j] = make_int4(0, 0, 0, 0);
    }
  }

  // ---- Single data pass: scalar sums + per-thread max keys (no atomics).
  unsigned km[NITER][4];                 // valid ? mono(y) : 0
  float uu[NITER][4], dd[NITER][4];
  int nv_l = 0;
  float sq = 0.f, sp = 0.f, seyy = 0.f, seyu = 0.f, aspu = 0.f, aspd = 0.f;
  unsigned tmax = 0u, tbmax = 0u;
#pragma unroll
  for (int j = 0; j < NITER; ++j) {
    const float* yp = (const float*)&y4[j];
    const float* upp = (const float*)&u4[j];
    const float* dp = (const float*)&d4[j];
    const int* mp = (const int*)&m4[j];
#pragma unroll
    for (int c = 0; c < 4; ++c) {
      const bool valid = mp[c] > 0;
      const float y = yp[c], u = upp[c], d = dp[c];
      uu[j][c] = u;
      dd[j][c] = d;
      const unsigned kd = valid ? mono_f32(y) : 0u;
      km[j][c] = kd;
      const unsigned kb = valid ? ~kd : 0u;
      tmax = kd > tmax ? kd : tmax;
      tbmax = kb > tbmax ? kb : tbmax;
      if (valid) {
        nv_l++;
        const float ey = __expf(y);
        sq += ey;
        seyy += ey * y;
        seyu += ey * u;
        sp += __expf(u);
        aspu += fmaxf(u, 0.f) + __logf(1.f + __expf(-fabsf(u)));
        aspd += fmaxf(d, 0.f) + __logf(1.f + __expf(-fabsf(d)));
      }
    }
  }

  // ---- Wave reduces of scalars.
  nv_l = wave_sum_i(nv_l);
  sq = wave_sum_f(sq);
  sp = wave_sum_f(sp);
  seyy = wave_sum_f(seyy);
  seyu = wave_sum_f(seyu);
  aspu = wave_sum_f(aspu);
  aspd = wave_sum_f(aspd);
  if (lane == 0) {
    red_i[wv] = nv_l;
    red_f[0][wv] = sq;  red_f[1][wv] = sp;
    red_f[2][wv] = seyy; red_f[3][wv] = seyu;
    red_f[4][wv] = aspu; red_f[5][wv] = aspd;
  }

  // ---- Per-wave filter threshold: 10th-largest thread-max (pop rounds).
  {
    unsigned v = tmax, t1 = 0u;
#pragma unroll 1
    for (int r = 0; r < TOPKK; ++r) {
      unsigned m = wave_max_u(v);
      if (v == m) v = 0u;
      t1 = m;
    }
    if (lane == 0) t1w_t[wv] = t1;
  }
  {
    unsigned v = tbmax, t1 = 0u;
#pragma unroll 1
    for (int r = 0; r < TOPKK; ++r) {
      unsigned m = wave_max_u(v);
      if (v == m) v = 0u;
      t1 = m;
    }
    if (lane == 0) t1w_b[wv] = t1;
  }
  __syncthreads();

  int nv = 0;
#pragma unroll
  for (int w = 0; w < NWAVES; ++w) nv += red_i[w];
  const int k = nv < TOPKK ? nv : TOPKK;

  unsigned t1 = 0u, t1b = 0u;
#pragma unroll
  for (int w = 0; w < NWAVES; ++w) {
    t1 = t1w_t[w] > t1 ? t1w_t[w] : t1;
    t1b = t1w_b[w] > t1b ? t1w_b[w] : t1b;
  }

  // ---- Compact candidates into LDS (few atomics; ~30-80 total per block).
#pragma unroll
  for (int j = 0; j < NITER; ++j) {
#pragma unroll
    for (int c = 0; c < 4; ++c) {
      const unsigned kd = km[j][c];
      if (kd != 0u) {
        if (kd >= t1) {
          int i = atomicAdd(&ct, 1);
          if (i < CAP) { keys_t[i] = kd; vals_t[i] = uu[j][c]; }
        }
        const unsigned kb = ~kd;
        if (kb >= t1b) {
          int i = atomicAdd(&cb, 1);
          if (i < CAP) { keys_b[i] = kb; vals_b[i] = dd[j][c]; }
        }
      }
    }
  }
  __syncthreads();

  // ---- Wave 0: exact k-th top key + label-weighted sum of u.
  if (wv == 0) {
    const int n = ct < CAP ? ct : CAP;
    unsigned kk[4]; float vvv[4];
#pragma unroll
    for (int i = 0; i < 4; ++i) {
      const int idx = i * 64 + lane;
      kk[i] = (idx < n) ? keys_t[idx] : 0u;
      vvv[i] = (idx < n) ? vals_t[idx] : 0.f;
    }
    unsigned w0 = kk[0], w1 = kk[1], w2 = kk[2], w3 = kk[3];
    unsigned thr = 0xFFFFFFFFu;
#pragma unroll 1
    for (int r = 0; r < k; ++r) {
      unsigned lm = w0 > w1 ? w0 : w1;
      unsigned lm2 = w2 > w3 ? w2 : w3;
      lm = lm > lm2 ? lm : lm2;
      unsigned m = wave_max_u(lm);
      if (w0 == m) w0 = 0u;
      else if (w1 == m) w1 = 0u;
      else if (w2 == m) w2 = 0u;
      else if (w3 == m) w3 = 0u;
      thr = m;
    }
    float su = 0.f;
#pragma unroll
    for (int i = 0; i < 4; ++i)
      if (kk[i] >= thr && kk[i] != 0u) su += vvv[i];
    su = wave_sum_f(su);
    if (lane == 0) s_res[0] = su;
  } else if (wv == 1) {
    // ---- Wave 1: exact k-th bottom key + label-weighted sum of d.
    const int n = cb < CAP ? cb : CAP;
    unsigned kk[4]; float vvv[4];
#pragma unroll
    for (int i = 0; i < 4; ++i) {
      const int idx = i * 64 + lane;
      kk[i] = (idx < n) ? keys_b[idx] : 0u;
      vvv[i] = (idx < n) ? vals_b[idx] : 0.f;
    }
    unsigned w0 = kk[0], w1 = kk[1], w2 = kk[2], w3 = kk[3];
    unsigned thr = 0xFFFFFFFFu;
#pragma unroll 1
    for (int r = 0; r < k; ++r) {
      unsigned lm = w0 > w1 ? w0 : w1;
      unsigned lm2 = w2 > w3 ? w2 : w3;
      lm = lm > lm2 ? lm : lm2;
      unsigned m = wave_max_u(lm);
      if (w0 == m) w0 = 0u;
      else if (w1 == m) w1 = 0u;
      else if (w2 == m) w2 = 0u;
      else if (w3 == m) w3 = 0u;
      thr = m;
    }
    float sd = 0.f;
#pragma unroll
    for (int i = 0; i < 4; ++i)
      if (kk[i] >= thr && kk[i] != 0u) sd += vvv[i];
    sd = wave_sum_f(sd);
    if (lane == 0) s_res[1] = sd;
  }
  __syncthreads();

  if (tid == 0 && nv > 0) {
    float SQ = 0.f, SP = 0.f, SYY = 0.f, SYU = 0.f, ASU = 0.f, ASD = 0.f;
#pragma unroll
    for (int w = 0; w < NWAVES; ++w) {
      SQ += red_f[0][w]; SP += red_f[1][w];
      SYY += red_f[2][w]; SYU += red_f[3][w];
      ASU += red_f[4][w]; ASD += red_f[5][w];
    }
    const float SU = s_res[0];
    const float SD = s_res[1];
    // KL closed form: sum q*(logq - logp) = (Seyy - Seyu)/Sq - log(Sq) + log(Sp)
    const float kl = (SYY - SYU) / SQ - __logf(SQ) + __logf(SP);
    const float up_loss = ASU - SU;  // sum softplus(u) - sum_{topk} u
    const float dn_loss = ASD - SD;  // sum softplus(d) - sum_{botk} d
    const float loss = (up_loss + 0.5f * dn_loss + 0.3f * kl) / (float)nv;
    atomicAdd(out, loss * inv_nrows);
  }
}

extern "C" void kernel_launch(void* const* d_in, const int* in_sizes, int n_in,
                              void* d_out, int out_size, void* d_ws, size_t ws_size,
                              hipStream_t stream) {
  const float* up_logits   = (const float*)d_in[0];
  const float* down_logits = (const float*)d_in[1];
  const float* y_true      = (const float*)d_in[2];
  const int*   masks       = (const int*)d_in[3];

  const int nrows = in_sizes[0] / NCOLS;

  hipMemsetAsync(d_out, 0, sizeof(float) * (size_t)out_size, stream);
  row_loss_kernel<<<nrows, BLOCK, 0, stream>>>(up_logits, down_logits, y_true,
                                               masks, (float*)d_out,
                                               1.0f / (float)nrows);
}

// Round 6
// 124.179 us; speedup vs baseline: 1.0500x; 1.0500x over previous
//
#include <hip/hip_runtime.h>
#include <math.h>

#define NCOLS 5000
#define NF4   1250            // NCOLS / 4
#define BLOCK 256
#define NWAVES (BLOCK / 64)
#define NITER 5               // ceil(NF4 / BLOCK)
#define TOPKK 10
#define CAP 128               // candidate capacity (expected ~40/block)

// Monotone-ascending mapping float -> uint32 (total order on finite floats).
__device__ __forceinline__ unsigned mono_f32(float f) {
  unsigned u = __float_as_uint(f);
  return (u & 0x80000000u) ? ~u : (u | 0x80000000u);
}

__device__ __forceinline__ float wave_sum_f(float v) {
#pragma unroll
  for (int o = 1; o < 64; o <<= 1) v += __shfl_xor(v, o);
  return v;
}
__device__ __forceinline__ int wave_sum_i(int v) {
#pragma unroll
  for (int o = 1; o < 64; o <<= 1) v += __shfl_xor(v, o);
  return v;
}
__device__ __forceinline__ unsigned wave_max_u(unsigned v) {
#pragma unroll
  for (int o = 1; o < 64; o <<= 1) {
    unsigned w = __shfl_xor(v, o);
    v = w > v ? w : v;
  }
  return v;
}

extern "C" __global__ __launch_bounds__(BLOCK, 4)
void row_loss_kernel(const float* __restrict__ up, const float* __restrict__ down,
                     const float* __restrict__ yt, const int* __restrict__ masks,
                     float* __restrict__ out, float inv_nrows) {
  __shared__ float red_f[6][NWAVES];   // sq, sp, seyy, seyu, aspu, aspd
  __shared__ int red_i[NWAVES];        // nv partials
  __shared__ unsigned t1w_t[NWAVES];   // per-wave 10th-largest thread-max (top)
  __shared__ unsigned t1w_b[NWAVES];   // same, bottom (~key space)
  __shared__ unsigned keys_t[CAP];     // top candidate keys
  __shared__ int      col_t[CAP];      // their column index
  __shared__ unsigned keys_b[CAP];     // bottom candidate keys (~key)
  __shared__ int      col_b[CAP];
  __shared__ int ct, cb;
  __shared__ float s_res[2];           // SU, SD

  const int tid = threadIdx.x;
  const int lane = tid & 63;
  const int wv = tid >> 6;
  const int row = blockIdx.x;
  const long long b4 = (long long)row * NF4;
  const long long base = (long long)row * NCOLS;

  const float4* up4 = (const float4*)up + b4;
  const float4* dn4 = (const float4*)down + b4;
  const float4* yt4 = (const float4*)yt + b4;
  const int4*   mk4 = (const int4*)masks + b4;

  if (tid == 0) { ct = 0; cb = 0; }

  // ---- 20 unconditional clamped vector loads, all issued upfront (MLP).
  float4 y4[NITER], u4[NITER], d4[NITER];
  int4 m4[NITER];
#pragma unroll
  for (int j = 0; j < NITER; ++j) {
    const int f = j * BLOCK + tid;
    const int fc = f < NF4 ? f : NF4 - 1;   // clamp, no branch around loads
    y4[j] = yt4[fc];
    u4[j] = up4[fc];
    d4[j] = dn4[fc];
    m4[j] = mk4[fc];
  }

  // ---- Single data pass: scalar sums + per-thread max keys.
  unsigned km[NITER][4];               // valid ? mono(y) : 0
  int nv_l = 0;
  float sq = 0.f, sp = 0.f, seyy = 0.f, seyu = 0.f, aspu = 0.f, aspd = 0.f;
  unsigned tmax = 0u, tbmax = 0u;
#pragma unroll
  for (int j = 0; j < NITER; ++j) {
    const bool inb = (j * BLOCK + tid) < NF4;
    const float* yp = (const float*)&y4[j];
    const float* upp = (const float*)&u4[j];
    const float* dp = (const float*)&d4[j];
    const int* mp = (const int*)&m4[j];
#pragma unroll
    for (int c = 0; c < 4; ++c) {
      const bool valid = inb && (mp[c] > 0);
      const float y = yp[c], u = upp[c], d = dp[c];
      const unsigned kd = valid ? mono_f32(y) : 0u;
      const unsigned kb = valid ? ~kd : 0u;
      km[j][c] = kd;
      tmax = kd > tmax ? kd : tmax;
      tbmax = kb > tbmax ? kb : tbmax;
      if (valid) {
        nv_l++;
        const float ey = __expf(y);
        sq += ey;
        seyy += ey * y;
        seyu += ey * u;
        sp += __expf(u);
        aspu += fmaxf(u, 0.f) + __logf(1.f + __expf(-fabsf(u)));
        aspd += fmaxf(d, 0.f) + __logf(1.f + __expf(-fabsf(d)));
      }
    }
  }

  // ---- Wave reduces of scalars.
  nv_l = wave_sum_i(nv_l);
  sq = wave_sum_f(sq);
  sp = wave_sum_f(sp);
  seyy = wave_sum_f(seyy);
  seyu = wave_sum_f(seyu);
  aspu = wave_sum_f(aspu);
  aspd = wave_sum_f(aspd);
  if (lane == 0) {
    red_i[wv] = nv_l;
    red_f[0][wv] = sq;  red_f[1][wv] = sp;
    red_f[2][wv] = seyy; red_f[3][wv] = seyu;
    red_f[4][wv] = aspu; red_f[5][wv] = aspd;
  }

  // ---- Per-wave filter threshold: 10th-largest thread-max (safe: >=10
  //      distinct elements >= t1 exist, so t1 <= exact k-th threshold).
  {
    unsigned v = tmax, t1 = 0u;
#pragma unroll 1
    for (int r = 0; r < TOPKK; ++r) {
      unsigned m = wave_max_u(v);
      if (v == m) v = 0u;
      t1 = m;
    }
    if (lane == 0) t1w_t[wv] = t1;
  }
  {
    unsigned v = tbmax, t1 = 0u;
#pragma unroll 1
    for (int r = 0; r < TOPKK; ++r) {
      unsigned m = wave_max_u(v);
      if (v == m) v = 0u;
      t1 = m;
    }
    if (lane == 0) t1w_b[wv] = t1;
  }
  __syncthreads();

  int nv = 0;
#pragma unroll
  for (int w = 0; w < NWAVES; ++w) nv += red_i[w];
  const int k = nv < TOPKK ? nv : TOPKK;

  unsigned t1 = 0u, t1b = 0u;
#pragma unroll
  for (int w = 0; w < NWAVES; ++w) {
    t1 = t1w_t[w] > t1 ? t1w_t[w] : t1;
    t1b = t1w_b[w] > t1b ? t1w_b[w] : t1b;
  }

  // ---- Compact candidate (key, column) pairs into LDS (~40 atomics total).
#pragma unroll
  for (int j = 0; j < NITER; ++j) {
#pragma unroll
    for (int c = 0; c < 4; ++c) {
      const unsigned kd = km[j][c];
      if (kd != 0u) {
        const int col = ((j * BLOCK + tid) << 2) + c;
        if (kd >= t1) {
          int i = atomicAdd(&ct, 1);
          if (i < CAP) { keys_t[i] = kd; col_t[i] = col; }
        }
        const unsigned kb = ~kd;
        if (kb >= t1b) {
          int i = atomicAdd(&cb, 1);
          if (i < CAP) { keys_b[i] = kb; col_b[i] = col; }
        }
      }
    }
  }
  __syncthreads();

  // ---- Wave 0: exact k-th top key, then Sum u over top-k (L2-warm reload).
  if (wv == 0) {
    const int n = ct < CAP ? ct : CAP;
    unsigned k0 = (lane < n) ? keys_t[lane] : 0u;
    unsigned k1 = (64 + lane < n) ? keys_t[64 + lane] : 0u;
    unsigned w0 = k0, w1 = k1;
    unsigned thr = 0xFFFFFFFFu;
#pragma unroll 1
    for (int r = 0; r < k; ++r) {
      unsigned m = wave_max_u(w0 > w1 ? w0 : w1);
      if (w0 == m) w0 = 0u;
      else if (w1 == m) w1 = 0u;
      thr = m;
    }
    float su = 0.f;
    if (k0 >= thr && k0 != 0u) su += up[base + col_t[lane]];
    if (k1 >= thr && k1 != 0u) su += up[base + col_t[64 + lane]];
    su = wave_sum_f(su);
    if (lane == 0) s_res[0] = su;
  } else if (wv == 1) {
    // ---- Wave 1: exact k-th bottom key, Sum d over bottom-k.
    const int n = cb < CAP ? cb : CAP;
    unsigned k0 = (lane < n) ? keys_b[lane] : 0u;
    unsigned k1 = (64 + lane < n) ? keys_b[64 + lane] : 0u;
    unsigned w0 = k0, w1 = k1;
    unsigned thr = 0xFFFFFFFFu;
#pragma unroll 1
    for (int r = 0; r < k; ++r) {
      unsigned m = wave_max_u(w0 > w1 ? w0 : w1);
      if (w0 == m) w0 = 0u;
      else if (w1 == m) w1 = 0u;
      thr = m;
    }
    float sd = 0.f;
    if (k0 >= thr && k0 != 0u) sd += down[base + col_b[lane]];
    if (k1 >= thr && k1 != 0u) sd += down[base + col_b[64 + lane]];
    sd = wave_sum_f(sd);
    if (lane == 0) s_res[1] = sd;
  }
  __syncthreads();

  if (tid == 0 && nv > 0) {
    float SQ = 0.f, SP = 0.f, SYY = 0.f, SYU = 0.f, ASU = 0.f, ASD = 0.f;
#pragma unroll
    for (int w = 0; w < NWAVES; ++w) {
      SQ += red_f[0][w]; SP += red_f[1][w];
      SYY += red_f[2][w]; SYU += red_f[3][w];
      ASU += red_f[4][w]; ASD += red_f[5][w];
    }
    const float SU = s_res[0];
    const float SD = s_res[1];
    // KL closed form: sum q*(logq - logp) = (Seyy - Seyu)/Sq - log(Sq) + log(Sp)
    const float kl = (SYY - SYU) / SQ - __logf(SQ) + __logf(SP);
    const float up_loss = ASU - SU;  // sum softplus(u) - sum_{topk} u
    const float dn_loss = ASD - SD;  // sum softplus(d) - sum_{botk} d
    const float loss = (up_loss + 0.5f * dn_loss + 0.3f * kl) / (float)nv;
    atomicAdd(out, loss * inv_nrows);
  }
}

extern "C" void kernel_launch(void* const* d_in, const int* in_sizes, int n_in,
                              void* d_out, int out_size, void* d_ws, size_t ws_size,
                              hipStream_t stream) {
  const float* up_logits   = (const float*)d_in[0];
  const float* down_logits = (const float*)d_in[1];
  const float* y_true      = (const float*)d_in[2];
  const int*   masks       = (const int*)d_in[3];

  const int nrows = in_sizes[0] / NCOLS;

  hipMemsetAsync(d_out, 0, sizeof(float) * (size_t)out_size, stream);
  row_loss_kernel<<<nrows, BLOCK, 0, stream>>>(up_logits, down_logits, y_true,
                                               masks, (float*)d_out,
                                               1.0f / (float)nrows);
}